// Round 9
// baseline (956.906 us; speedup 1.0000x reference)
//
#include <hip/hip_runtime.h>
#include <hip/hip_bf16.h>

// Problem dims (TransformerDecoder): L=6, B=1, S=2048, D=1024, H=16, DH=64, FF=4096
constexpr int S_  = 2048;
constexpr int D_  = 1024;
constexpr int H_  = 16;
constexpr int DH_ = 64;
constexpr int FF_ = 4096;
constexpr int L_  = 6;
constexpr int DQKV_ = 3 * D_;

typedef __attribute__((ext_vector_type(8))) short short8;   // 8 bf16 = 4 VGPR (MFMA A/B frag)
typedef __attribute__((ext_vector_type(4))) short s16x4;
typedef __attribute__((ext_vector_type(4))) float f32x4;    // MFMA C/D frag

__device__ inline short f2bf(float x) {
  __hip_bfloat16 h = __float2bfloat16(x);
  short s; __builtin_memcpy(&s, &h, 2); return s;
}
__device__ inline float bf2f(short s) {
  unsigned int u = ((unsigned int)(unsigned short)s) << 16;
  float f; __builtin_memcpy(&f, &u, 4); return f;
}
__device__ inline unsigned int pack2bf(float a, float b) {
  return (unsigned int)(unsigned short)f2bf(a) |
         ((unsigned int)(unsigned short)f2bf(b) << 16);
}

// async global->LDS, 16B per lane (LDS dst must be wave-uniform base + lane*16)
__device__ inline void gl2lds16(const void* g, void* l) {
  __builtin_amdgcn_global_load_lds(
      (const __attribute__((address_space(1))) unsigned int*)g,
      (__attribute__((address_space(3))) unsigned int*)l, 16, 0, 0);
}

// LDS swizzle for 128B-row tiles (involution, 16B granular): XOR byte bits 4-6
// with row&7 (bits 7-9). Applied BOTH sides (pre-swizzled source order for the
// linear global_load_lds dst + swizzled ds_read address) — rule 21.
__device__ inline int swz128(int x) { return x ^ (((x >> 7) & 7) << 4); }

// ---------------------------------------------------------------------------
// Deep-pipelined NT GEMM (T2+T3+T4+T5): C[m][n] = sum_k A[m][k]*Bt[n][k]
// 256x128 tile, BK=64, 8 waves (2Mx4N), double-buffered LDS (96 KB),
// counted vmcnt(6) — loads stay in flight across barriers (never 0 mid-loop).
// B operand is in TILE-BLOB format: each 128n x 64k tile is one contiguous
// 16 KB blob, pre-arranged in physical (post-swizzle) LDS staging order.
// Blob index = (n0/128)*kTilesTot + kt. B staging is therefore a pure linear
// copy. Split-K via blockIdx.z: A advances sAz elements, B advances kbz tiles.
// VTOUT (QKV): columns >= 2*D_ are V -> written transposed to vTout[H][DH][S].
// (R5 fused-fp32-B: +173us regression. R7 wp-fusion: marginal accuracy fail.
//  This is the verified R3/R8 configuration — the session's best state.)
// ---------------------------------------------------------------------------
template<bool BIAS, bool RELU, bool OUTBF, bool VTOUT>
__global__ __launch_bounds__(512, 2) void gemm8p(
    const short* __restrict__ A, int lda, long long sAz,
    const short* __restrict__ Bt, int kTilesTot, int kbz,
    void* __restrict__ Cv, int ldc, long long sCz,
    const float* __restrict__ bias, int K, short* __restrict__ vTout)
{
  constexpr int BM = 256, BN = 128, BK = 64;
  const int m0 = blockIdx.x * BM, n0 = blockIdx.y * BN;
  A += (long long)blockIdx.z * sAz;
  const short* Bbase = Bt +
      ((size_t)(n0 >> 7) * kTilesTot + (size_t)blockIdx.z * kbz) * (BN * BK);

  __shared__ __align__(16) short lds[2][(BM + BN) * BK];  // [buf][A 256x64 | B 128x64]

  const int tid  = threadIdx.x;
  const int lane = tid & 63, wave = tid >> 6;
  const int wr = wave >> 2, wc = wave & 3;       // 2M x 4N wave grid
  const int r16 = lane & 15, g = lane >> 4;

  f32x4 acc[8][2];
#pragma unroll
  for (int m = 0; m < 8; m++)
#pragma unroll
    for (int n = 0; n < 2; n++) acc[m][n] = f32x4{0.f, 0.f, 0.f, 0.f};

  const int NT = K / BK;

  auto stage = [&](int buf, int t) {
    char* base = (char*)lds[buf];
    // A tile: 256 rows x 64 k (32 KB) = 4 rounds of 512 threads x 16B
#pragma unroll
    for (int r = 0; r < 4; r++) {
      int p = r * 8192 + tid * 16;       // physical LDS byte (linear dst)
      int q = swz128(p);                 // logical tile byte
      int row = q >> 7, kc = (q & 127) >> 1;
      gl2lds16(&A[(size_t)(m0 + row) * lda + t * BK + kc], base + p);
    }
    // B tile: one 16 KB blob, already in physical order -> linear copy
    const short* btile = Bbase + (size_t)t * (BN * BK);
#pragma unroll
    for (int r = 0; r < 2; r++) {
      int p = r * 8192 + tid * 16;
      gl2lds16((const char*)btile + p, base + BM * BK * 2 + p);
    }
  };

  stage(0, 0);
  for (int t = 0; t < NT; t++) {
    __builtin_amdgcn_s_barrier();        // all waves done reading buf[(t+1)&1]
    asm volatile("" ::: "memory");
    if (t + 1 < NT) {
      stage((t + 1) & 1, t + 1);         // 6 loads -> in flight across barriers
      asm volatile("s_waitcnt vmcnt(6)" ::: "memory");   // tile t landed (T4)
    } else {
      asm volatile("s_waitcnt vmcnt(0)" ::: "memory");   // epilogue drain
    }
    __builtin_amdgcn_s_barrier();        // all waves confirmed their loads
    asm volatile("" ::: "memory");

    const char* sa = (const char*)lds[t & 1];
    const char* sb = (const char*)lds[t & 1] + BM * BK * 2;
    const int xo = (r16 & 7) << 4;       // read-side swizzle

    short8 af[8][2], bfr[2][2];
#pragma unroll
    for (int fm = 0; fm < 8; fm++)
#pragma unroll
      for (int kk = 0; kk < 2; kk++) {
        int row = wr * 128 + fm * 16 + r16;
        af[fm][kk] = *(const short8*)(sa + row * 128 + ((kk * 64 + g * 16) ^ xo));
      }
#pragma unroll
    for (int nq = 0; nq < 2; nq++)
#pragma unroll
      for (int kk = 0; kk < 2; kk++) {
        int row = wc * 32 + nq * 16 + r16;
        bfr[nq][kk] = *(const short8*)(sb + row * 128 + ((kk * 64 + g * 16) ^ xo));
      }

    __builtin_amdgcn_s_setprio(1);
#pragma unroll
    for (int fm = 0; fm < 8; fm++)
#pragma unroll
      for (int nq = 0; nq < 2; nq++)
#pragma unroll
        for (int kk = 0; kk < 2; kk++)
          acc[fm][nq] = __builtin_amdgcn_mfma_f32_16x16x32_bf16(
              af[fm][kk], bfr[nq][kk], acc[fm][nq], 0, 0, 0);
    __builtin_amdgcn_s_setprio(0);
  }

  // epilogue — verified C/D layout: col = lane&15, row = (lane>>4)*4 + j
  const int rw = g * 4;
#pragma unroll
  for (int am = 0; am < 8; am++) {
#pragma unroll
    for (int an = 0; an < 2; an++) {
      const int rg = m0 + wr * 128 + am * 16 + rw;
      const int cg = n0 + wc * 32 + an * 16 + r16;
      float bv = 0.f;
      if (BIAS) { if (blockIdx.z == 0) bv = bias[cg]; }
      if (VTOUT && cg >= 2 * D_) {       // V columns -> vT[h][d][s] (s = rg..rg+3)
        int hh = (cg - 2 * D_) >> 6, dd = (cg - 2 * D_) & 63;
        s16x4 ov;
#pragma unroll
        for (int j = 0; j < 4; j++) ov[j] = f2bf(acc[am][an][j]);
        *(s16x4*)&vTout[(size_t)hh * DH_ * S_ + (size_t)dd * S_ + rg] = ov;
      } else {
#pragma unroll
        for (int j = 0; j < 4; j++) {
          float v = acc[am][an][j] + bv;
          if (RELU) v = fmaxf(v, 0.f);
          if (OUTBF)
            ((short*)Cv + (long long)blockIdx.z * sCz)[(size_t)(rg + j) * ldc + cg] = f2bf(v);
          else
            ((float*)Cv + (long long)blockIdx.z * sCz)[(size_t)(rg + j) * ldc + cg] = v;
        }
      }
    }
  }
}

// ---------------------------------------------------------------------------
// Flash attention (causal, online softmax). 512 blocks, 256 threads.
// XCD-chunked swizzle: all 32 q-blocks of a head land on one XCD (K/V L2
// reuse); heavy q-blocks first within each XCD sequence.
// Swapped QK^T (mfma(K,Q)) -> score rows lane-local; P via wave-private LDS.
// K/V^T double-buffered; one barrier per KV step; setprio around MFMA (T5).
// (Verified R3 body — R6 softmax restructure regressed +27us, reverted.)
// ---------------------------------------------------------------------------
__global__ __launch_bounds__(256, 4) void flash_attn(
    const short* __restrict__ qkv, const short* __restrict__ vT,
    short* __restrict__ attno)
{
  const int f = blockIdx.y * gridDim.x + blockIdx.x;
  const int xcd = f & 7, i = f >> 3;
  const int h  = xcd * 2 + (i >> 5);
  const int qb = (31 - (i & 31)) * 64;               // heavy blocks first
  const int tid = threadIdx.x, lane = tid & 63, w = tid >> 6;
  const int r16 = lane & 15, g = lane >> 4, kg = g * 8;

  __shared__ __align__(16) short kv_lds[2][2][64 * 64];
  __shared__ __align__(16) short p_lds[4][16 * 64];

  short8 qreg[2];
  {
    const short* qrow = qkv + (size_t)(qb + w * 16 + r16) * DQKV_ + h * DH_;
    qreg[0] = *(const short8*)&qrow[kg];
    qreg[1] = *(const short8*)&qrow[32 + kg];
  }

  const short* Ksec = qkv + D_ + h * DH_;
  const short* Vsec = vT + (size_t)h * DH_ * S_;

  auto stageKV = [&](int buf, int kv0) {
#pragma unroll
    for (int r = 0; r < 2; r++) {
      int p = r * 4096 + tid * 16;
      int q = swz128(p);
      int row = q >> 7, col = (q & 127) >> 1;
      gl2lds16(&Ksec[(size_t)(kv0 + row) * DQKV_ + col], (char*)kv_lds[buf][0] + p);
    }
#pragma unroll
    for (int r = 0; r < 2; r++) {
      int p = r * 4096 + tid * 16;
      int q = swz128(p);
      int row = q >> 7, col = (q & 127) >> 1;
      gl2lds16(&Vsec[(size_t)row * S_ + kv0 + col], (char*)kv_lds[buf][1] + p);
    }
  };

  f32x4 sacc[4], oacc[4];
#pragma unroll
  for (int m = 0; m < 4; m++) oacc[m] = f32x4{0.f, 0.f, 0.f, 0.f};
  float mrow = -3.0e38f, lrow = 0.f;
  const int qrow_g = qb + w * 16 + r16;
  const int nsteps = qb / 64 + 1;

  stageKV(0, 0);
  int cur = 0;
  for (int s = 0; s < nsteps; s++) {
    __syncthreads();
    if (s + 1 < nsteps) stageKV(cur ^ 1, (s + 1) * 64);

#pragma unroll
    for (int m = 0; m < 4; m++) sacc[m] = f32x4{0.f, 0.f, 0.f, 0.f};
    __builtin_amdgcn_s_setprio(1);
#pragma unroll
    for (int kk = 0; kk < 2; kk++) {
#pragma unroll
      for (int m = 0; m < 4; m++) {
        int lb = (m * 16 + r16) * 128 + (((kk * 32 + kg) * 2) ^ ((r16 & 7) << 4));
        short8 kf = *(const short8*)((const char*)kv_lds[cur][0] + lb);
        sacc[m] = __builtin_amdgcn_mfma_f32_16x16x32_bf16(kf, qreg[kk], sacc[m], 0, 0, 0);
      }
    }
    __builtin_amdgcn_s_setprio(0);

    const int kv0 = s * 64;
    const bool diag = (s == nsteps - 1);
    float mx = mrow;
#pragma unroll
    for (int m = 0; m < 4; m++)
#pragma unroll
      for (int j = 0; j < 4; j++) {
        float x = sacc[m][j] * 0.125f;
        if (diag && (kv0 + m * 16 + g * 4 + j > qrow_g)) x = -3.0e38f;
        sacc[m][j] = x;
        mx = fmaxf(mx, x);
      }
    mx = fmaxf(mx, __shfl_xor(mx, 16));
    mx = fmaxf(mx, __shfl_xor(mx, 32));
    float alpha = __expf(mrow - mx);
    mrow = mx;

    float psum = 0.f;
#pragma unroll
    for (int m = 0; m < 4; m++) {
      s16x4 pk;
#pragma unroll
      for (int j = 0; j < 4; j++) {
        float p = __expf(sacc[m][j] - mx);
        psum += p;
        pk[j] = f2bf(p);
      }
      *(s16x4*)((char*)p_lds[w] + r16 * 128 + (((m * 16 + g * 4) * 2) ^ ((r16 & 7) << 4))) = pk;
    }
    psum += __shfl_xor(psum, 16);
    psum += __shfl_xor(psum, 32);
    lrow = lrow * alpha + psum;

#pragma unroll
    for (int m = 0; m < 4; m++)
#pragma unroll
      for (int j = 0; j < 4; j++) oacc[m][j] *= alpha;

    __builtin_amdgcn_s_setprio(1);
#pragma unroll
    for (int kk = 0; kk < 2; kk++) {
      int pb = r16 * 128 + (((kk * 32 + kg) * 2) ^ ((r16 & 7) << 4));
      short8 pf = *(const short8*)((const char*)p_lds[w] + pb);
#pragma unroll
      for (int m = 0; m < 4; m++) {
        int vb = (m * 16 + r16) * 128 + (((kk * 32 + kg) * 2) ^ ((r16 & 7) << 4));
        short8 vf = *(const short8*)((const char*)kv_lds[cur][1] + vb);
        oacc[m] = __builtin_amdgcn_mfma_f32_16x16x32_bf16(vf, pf, oacc[m], 0, 0, 0);
      }
    }
    __builtin_amdgcn_s_setprio(0);
    cur ^= 1;
  }

  float inv = 1.0f / lrow;
  short* orow = attno + (size_t)qrow_g * D_ + h * DH_;
#pragma unroll
  for (int m = 0; m < 4; m++) {
    s16x4 ov;
#pragma unroll
    for (int j = 0; j < 4; j++) ov[j] = f2bf(oacc[m][j] * inv);
    *(s16x4*)&orow[m * 16 + g * 4] = ov;
  }
}

// ---------------------------------------------------------------------------
// Weight prep v3.1 body (verified @942us), now launched PER LAYER (6 x 1536
// blocks) so no single >100us dispatch hides the rest of the pipeline from
// the rocprof top-5. Semantics identical: same wp tile body, same blob
// addresses, stream-ordered before first use.
// Tiles/layer: QKV 3*128=384 + Wo 128 + W1 512 + W2 512 = 1536.
// Pinned at ~2.7-2.9 TB/s across 4 structural variants (R1/R3/R4) — the
// fp32->bf16 transpose at this size is structure-invariant; do not re-polish.
// ---------------------------------------------------------------------------
__global__ __launch_bounds__(256) void weight_prep(
    const float* __restrict__ Wq, const float* __restrict__ Wk,
    const float* __restrict__ Wv, const float* __restrict__ Wo,
    const float* __restrict__ W1, const float* __restrict__ W2,
    short* __restrict__ WqkvT, short* __restrict__ WoT,
    short* __restrict__ W1T, short* __restrict__ W2T, int l)
{
  const int r = blockIdx.x;
  const float* src; short* dstb; int N, t, ks;
  if (r < 384) {
    int which = r >> 7; t = r & 127;
    src  = (which == 0 ? Wq : which == 1 ? Wk : Wv) + (size_t)l * D_ * D_;
    dstb = WqkvT + (size_t)l * DQKV_ * D_ + (size_t)which * D_ * D_;
    N = D_; ks = 4;
  } else if (r < 512) {
    t = r - 384;
    src = Wo + (size_t)l * D_ * D_; dstb = WoT + (size_t)l * D_ * D_;
    N = D_; ks = 4;
  } else if (r < 1024) {
    t = r - 512;
    src = W1 + (size_t)l * D_ * FF_; dstb = W1T + (size_t)l * D_ * FF_;
    N = FF_; ks = 4;
  } else {
    t = r - 1024;
    src = W2 + (size_t)l * D_ * FF_; dstb = W2T + (size_t)l * D_ * FF_;
    N = D_; ks = 6;
  }
  const int kT = 1 << ks;
  const int nt = t >> ks, kt = t & (kT - 1);
  const int n0 = nt * 128, k0 = kt * 64;
  short* out = dstb + ((size_t)nt * kT + kt) * (128 * 64);  // 16 KB blob

  // staging tile [k][n] bf16, pitch 130 shorts: phase-1 writes 2-way (free)
  __shared__ short tile[64][130];
  const int tid = threadIdx.x;

  // Phase 1: 64 rows x 128 cols fp32, 8 float4/thread, all in flight first
  {
    const int kr = tid >> 5;            // 0..7
    const int c4 = (tid & 31) * 4;      // 0..124
    const float* sp = &src[(size_t)(k0 + kr) * N + n0 + c4];
    float4 f[8];
#pragma unroll
    for (int i = 0; i < 8; i++) f[i] = *(const float4*)(sp + (size_t)i * 8 * N);
#pragma unroll
    for (int i = 0; i < 8; i++) {
      unsigned int* pw = (unsigned int*)&tile[kr + i * 8][c4];
      pw[0] = pack2bf(f[i].x, f[i].y);
      pw[1] = pack2bf(f[i].z, f[i].w);
    }
  }
  __syncthreads();

  // Phase 2: blob byte p -> logical q = swz128(p): n = q>>7, k = (q&127)>>1.
  // Gather 8 k-consecutive shorts of one n -> short8 -> linear 16B store.
#pragma unroll
  for (int rr = 0; rr < 4; rr++) {
    const int p = (rr * 256 + tid) * 16;
    const int q = swz128(p);
    const int n = q >> 7, k = (q & 127) >> 1;
    short8 o;
#pragma unroll
    for (int j = 0; j < 8; j++) o[j] = tile[k + j][n];
    *(short8*)((char*)out + p) = o;
  }
}

// ---------------------------------------------------------------------------
// Embedding + sinusoidal PE -> h fp32, hb bf16. grid = S, block = 256
// powf(1e4,e) -> exp2f(-13.2877*e): same value (verified passing in R6/R8).
// ---------------------------------------------------------------------------
__global__ __launch_bounds__(256) void embed_kernel(
    const int* __restrict__ tok, const float* __restrict__ emb,
    float* __restrict__ h, short* __restrict__ hb)
{
  int s = blockIdx.x, t = threadIdx.x;
  int token = tok[s];
  int d0 = t * 4;
  float4 e = *(const float4*)&emb[(size_t)token * D_ + d0];
  float o[4] = {e.x, e.y, e.z, e.w};
#pragma unroll
  for (int c = 0; c < 4; c++) {
    int d = d0 + c;
    float expo = (float)(d & ~1) / (float)D_;
    float ang  = (float)s * exp2f(expo * -13.287712379549449f);
    o[c] += (d & 1) ? cosf(ang) : sinf(ang);
  }
  float4 ov = {o[0], o[1], o[2], o[3]};
  *(float4*)&h[(size_t)s * D_ + d0] = ov;
  s16x4 sv = {f2bf(o[0]), f2bf(o[1]), f2bf(o[2]), f2bf(o[3])};
  *(s16x4*)&hb[(size_t)s * D_ + d0] = sv;
}

// ---------------------------------------------------------------------------
// out = LayerNorm(sum_z px[z] (bf16 partials) + x32 + res) * g + b
// fp32 out + optional bf16 outb. px or x32 may be null.
// ---------------------------------------------------------------------------
__global__ __launch_bounds__(256) void add_ln_kernel(
    const short* __restrict__ px, int nx, long long xs,
    const float* __restrict__ x32,
    const float* __restrict__ res,
    const float* __restrict__ g, const float* __restrict__ b,
    float* __restrict__ out, short* __restrict__ outb)
{
  int row = blockIdx.x, t = threadIdx.x;
  size_t base = (size_t)row * D_ + t * 4;
  float4 v = {0.f, 0.f, 0.f, 0.f};
  if (px) {
    for (int z = 0; z < nx; z++) {
      s16x4 r = *(const s16x4*)&px[(size_t)z * xs + base];
      v.x += bf2f(r[0]); v.y += bf2f(r[1]); v.z += bf2f(r[2]); v.w += bf2f(r[3]);
    }
  }
  if (x32) {
    float4 r = *(const float4*)&x32[base];
    v.x += r.x; v.y += r.y; v.z += r.z; v.w += r.w;
  }
  if (res) {
    float4 r = *(const float4*)&res[base];
    v.x += r.x; v.y += r.y; v.z += r.z; v.w += r.w;
  }
  float s  = v.x + v.y + v.z + v.w;
  float ss = v.x * v.x + v.y * v.y + v.z * v.z + v.w * v.w;
#pragma unroll
  for (int o = 32; o; o >>= 1) { s += __shfl_xor(s, o); ss += __shfl_xor(ss, o); }
  __shared__ float sh[8];
  int w = t >> 6;
  if ((t & 63) == 0) { sh[w] = s; sh[4 + w] = ss; }
  __syncthreads();
  s  = sh[0] + sh[1] + sh[2] + sh[3];
  ss = sh[4] + sh[5] + sh[6] + sh[7];
  float mean = s * (1.0f / D_);
  float var  = ss * (1.0f / D_) - mean * mean;
  float rinv = rsqrtf(var + 1e-5f);
  float4 gv = *(const float4*)&g[t * 4];
  float4 bv = *(const float4*)&b[t * 4];
  float4 ov;
  ov.x = (v.x - mean) * rinv * gv.x + bv.x;
  ov.y = (v.y - mean) * rinv * gv.y + bv.y;
  ov.z = (v.z - mean) * rinv * gv.z + bv.z;
  ov.w = (v.w - mean) * rinv * gv.w + bv.w;
  *(float4*)&out[base] = ov;
  if (outb) {
    s16x4 sv = {f2bf(ov.x), f2bf(ov.y), f2bf(ov.z), f2bf(ov.w)};
    *(s16x4*)&outb[base] = sv;
  }
}

__global__ void fill_kernel(float* out, int n, float v) {
  int i = blockIdx.x * 256 + threadIdx.x;
  if (i < n) out[i] = v;
}

// ---------------------------------------------------------------------------
extern "C" void kernel_launch(void* const* d_in, const int* in_sizes, int n_in,
                              void* d_out, int out_size, void* d_ws, size_t ws_size,
                              hipStream_t stream)
{
  const int*   tokens = (const int*)  d_in[0];
  const float* emb    = (const float*)d_in[1];
  const float* Wq     = (const float*)d_in[2];
  const float* Wk     = (const float*)d_in[3];
  const float* Wv     = (const float*)d_in[4];
  const float* Wo     = (const float*)d_in[5];
  const float* ln1_g  = (const float*)d_in[6];
  const float* ln1_b  = (const float*)d_in[7];
  const float* W1     = (const float*)d_in[8];
  const float* b1     = (const float*)d_in[9];
  const float* W2     = (const float*)d_in[10];
  const float* b2     = (const float*)d_in[11];
  const float* ln2_g  = (const float*)d_in[12];
  const float* ln2_b  = (const float*)d_in[13];
  const float* post_g = (const float*)d_in[14];
  const float* post_b = (const float*)d_in[15];

  size_t off = 0;
  auto alloc = [&](size_t bytes) -> char* {
    char* p = (char*)d_ws + off;
    off = (off + bytes + 255) & ~(size_t)255;
    return p;
  };
  short* WqkvT = (short*)alloc((size_t)L_ * DQKV_ * D_ * 2);
  short* WoT   = (short*)alloc((size_t)L_ * D_ * D_ * 2);
  short* W1T   = (short*)alloc((size_t)L_ * D_ * FF_ * 2);
  short* W2T   = (short*)alloc((size_t)L_ * D_ * FF_ * 2);
  float* h     = (float*)alloc((size_t)S_ * D_ * 4);
  short* hb    = (short*)alloc((size_t)S_ * D_ * 2);
  short* qkv   = (short*)alloc((size_t)S_ * DQKV_ * 2);
  short* vT    = (short*)alloc((size_t)S_ * D_ * 2);
  short* attno = (short*)alloc((size_t)S_ * D_ * 2);
  short* part  = (short*)alloc((size_t)4 * S_ * D_ * 2);   // bf16 split-K partials
  float* h1    = (float*)alloc((size_t)S_ * D_ * 4);
  short* h1b   = (short*)alloc((size_t)S_ * D_ * 2);
  short* m1    = (short*)alloc((size_t)S_ * FF_ * 2);

  if (off > ws_size) {
    fill_kernel<<<(out_size + 255) / 256, 256, 0, stream>>>(
        (float*)d_out, out_size, (float)(ws_size >> 20));
    return;
  }

  // per-layer weight prep (6 x 1536 blocks) — same work as the single
  // (1536, L) launch, split so rocprof top-5 can see the rest of the pipeline
  for (int l = 0; l < L_; l++)
    weight_prep<<<1536, 256, 0, stream>>>(
        Wq, Wk, Wv, Wo, W1, W2, WqkvT, WoT, W1T, W2T, l);

  embed_kernel<<<S_, 256, 0, stream>>>(tokens, emb, h, hb);

  for (int l = 0; l < L_; l++) {
    const short* wqkv = WqkvT + (size_t)l * DQKV_ * D_;
    const short* wot  = WoT + (size_t)l * D_ * D_;
    const short* w1t  = W1T + (size_t)l * D_ * FF_;
    const short* w2t  = W2T + (size_t)l * D_ * FF_;

    // fused QKV: [2048,1024] x [3072,1024]^T; V columns go straight to vT
    gemm8p<false, false, true, true>
        <<<dim3(S_ / 256, DQKV_ / 128, 1), 512, 0, stream>>>(
            hb, D_, 0, wqkv, 16, 0, qkv, DQKV_, 0, nullptr, D_, vT);

    // fused causal attention -> attno [S][D]
    flash_attn<<<dim3(S_ / 64, H_), 256, 0, stream>>>(qkv, vT, attno);

    // o = attno @ Wo, split-K=4 -> bf16 partials (256 blocks)
    gemm8p<false, false, true, false>
        <<<dim3(S_ / 256, D_ / 128, 4), 512, 0, stream>>>(
            attno, D_, D_ / 4, wot, 16, 4,
            part, D_, (long long)S_ * D_, nullptr, D_ / 4, nullptr);

    add_ln_kernel<<<S_, 256, 0, stream>>>(part, 4, (long long)S_ * D_, nullptr, h,
                                          ln1_g + (size_t)l * D_,
                                          ln1_b + (size_t)l * D_, h1, h1b);

    // MLP1: relu(h1 @ W1 + b1) (256 blocks)
    gemm8p<true, true, true, false>
        <<<dim3(S_ / 256, FF_ / 128, 1), 512, 0, stream>>>(
            h1b, D_, 0, w1t, 16, 0, m1, FF_, 0, b1 + (size_t)l * FF_, D_, nullptr);

    // MLP2: m1 @ W2 + b2, split-K=4 -> bf16 partials (256 blocks)
    gemm8p<true, false, true, false>
        <<<dim3(S_ / 256, D_ / 128, 4), 512, 0, stream>>>(
            m1, FF_, FF_ / 4, w2t, 64, 16,
            part, D_, (long long)S_ * D_, b2 + (size_t)l * D_, FF_ / 4, nullptr);

    add_ln_kernel<<<S_, 256, 0, stream>>>(part, 4, (long long)S_ * D_, nullptr, h1,
                                          ln2_g + (size_t)l * D_,
                                          ln2_b + (size_t)l * D_, h, hb);
  }

  add_ln_kernel<<<S_, 256, 0, stream>>>(nullptr, 0, 0, h, nullptr, post_g, post_b,
                                        (float*)d_out, nullptr);
}

// Round 10
// 941.320 us; speedup vs baseline: 1.0166x; 1.0166x over previous
//
#include <hip/hip_runtime.h>
#include <hip/hip_bf16.h>

// Problem dims (TransformerDecoder): L=6, B=1, S=2048, D=1024, H=16, DH=64, FF=4096
constexpr int S_  = 2048;
constexpr int D_  = 1024;
constexpr int H_  = 16;
constexpr int DH_ = 64;
constexpr int FF_ = 4096;
constexpr int L_  = 6;
constexpr int DQKV_ = 3 * D_;

typedef __attribute__((ext_vector_type(8))) short short8;   // 8 bf16 = 4 VGPR (MFMA A/B frag)
typedef __attribute__((ext_vector_type(4))) short s16x4;
typedef __attribute__((ext_vector_type(4))) float f32x4;    // MFMA C/D frag

__device__ inline short f2bf(float x) {
  __hip_bfloat16 h = __float2bfloat16(x);
  short s; __builtin_memcpy(&s, &h, 2); return s;
}
__device__ inline float bf2f(short s) {
  unsigned int u = ((unsigned int)(unsigned short)s) << 16;
  float f; __builtin_memcpy(&f, &u, 4); return f;
}
__device__ inline unsigned int pack2bf(float a, float b) {
  return (unsigned int)(unsigned short)f2bf(a) |
         ((unsigned int)(unsigned short)f2bf(b) << 16);
}

// async global->LDS, 16B per lane (LDS dst must be wave-uniform base + lane*16)
__device__ inline void gl2lds16(const void* g, void* l) {
  __builtin_amdgcn_global_load_lds(
      (const __attribute__((address_space(1))) unsigned int*)g,
      (__attribute__((address_space(3))) unsigned int*)l, 16, 0, 0);
}

// LDS swizzle for 128B-row tiles (involution, 16B granular): XOR byte bits 4-6
// with row&7 (bits 7-9). Applied BOTH sides (pre-swizzled source order for the
// linear global_load_lds dst + swizzled ds_read address) — rule 21.
__device__ inline int swz128(int x) { return x ^ (((x >> 7) & 7) << 4); }

// ---------------------------------------------------------------------------
// Deep-pipelined NT GEMM (T2+T3+T4+T5): C[m][n] = sum_k A[m][k]*Bt[n][k]
// 256x128 tile, BK=64, 8 waves (2Mx4N), double-buffered LDS (96 KB),
// counted vmcnt(6) — loads stay in flight across barriers (never 0 mid-loop).
// B operand is in TILE-BLOB format: each 128n x 64k tile is one contiguous
// 16 KB blob, pre-arranged in physical (post-swizzle) LDS staging order.
// Blob index = (n0/128)*kTilesTot + kt. B staging is therefore a pure linear
// copy. Split-K via blockIdx.z: A advances sAz elements, B advances kbz tiles.
// VTOUT (QKV): columns >= 2*D_ are V -> written transposed to vTout[H][DH][S].
// Session ledger: R5 fused-fp32-B −173us; R6 softmax rework −27us; R7 wp-fusion
// accuracy fail; R9 per-layer wp split −14us. This R8 config = verified best.
// ---------------------------------------------------------------------------
template<bool BIAS, bool RELU, bool OUTBF, bool VTOUT>
__global__ __launch_bounds__(512, 2) void gemm8p(
    const short* __restrict__ A, int lda, long long sAz,
    const short* __restrict__ Bt, int kTilesTot, int kbz,
    void* __restrict__ Cv, int ldc, long long sCz,
    const float* __restrict__ bias, int K, short* __restrict__ vTout)
{
  constexpr int BM = 256, BN = 128, BK = 64;
  const int m0 = blockIdx.x * BM, n0 = blockIdx.y * BN;
  A += (long long)blockIdx.z * sAz;
  const short* Bbase = Bt +
      ((size_t)(n0 >> 7) * kTilesTot + (size_t)blockIdx.z * kbz) * (BN * BK);

  __shared__ __align__(16) short lds[2][(BM + BN) * BK];  // [buf][A 256x64 | B 128x64]

  const int tid  = threadIdx.x;
  const int lane = tid & 63, wave = tid >> 6;
  const int wr = wave >> 2, wc = wave & 3;       // 2M x 4N wave grid
  const int r16 = lane & 15, g = lane >> 4;

  f32x4 acc[8][2];
#pragma unroll
  for (int m = 0; m < 8; m++)
#pragma unroll
    for (int n = 0; n < 2; n++) acc[m][n] = f32x4{0.f, 0.f, 0.f, 0.f};

  const int NT = K / BK;

  auto stage = [&](int buf, int t) {
    char* base = (char*)lds[buf];
    // A tile: 256 rows x 64 k (32 KB) = 4 rounds of 512 threads x 16B
#pragma unroll
    for (int r = 0; r < 4; r++) {
      int p = r * 8192 + tid * 16;       // physical LDS byte (linear dst)
      int q = swz128(p);                 // logical tile byte
      int row = q >> 7, kc = (q & 127) >> 1;
      gl2lds16(&A[(size_t)(m0 + row) * lda + t * BK + kc], base + p);
    }
    // B tile: one 16 KB blob, already in physical order -> linear copy
    const short* btile = Bbase + (size_t)t * (BN * BK);
#pragma unroll
    for (int r = 0; r < 2; r++) {
      int p = r * 8192 + tid * 16;
      gl2lds16((const char*)btile + p, base + BM * BK * 2 + p);
    }
  };

  stage(0, 0);
  for (int t = 0; t < NT; t++) {
    __builtin_amdgcn_s_barrier();        // all waves done reading buf[(t+1)&1]
    asm volatile("" ::: "memory");
    if (t + 1 < NT) {
      stage((t + 1) & 1, t + 1);         // 6 loads -> in flight across barriers
      asm volatile("s_waitcnt vmcnt(6)" ::: "memory");   // tile t landed (T4)
    } else {
      asm volatile("s_waitcnt vmcnt(0)" ::: "memory");   // epilogue drain
    }
    __builtin_amdgcn_s_barrier();        // all waves confirmed their loads
    asm volatile("" ::: "memory");

    const char* sa = (const char*)lds[t & 1];
    const char* sb = (const char*)lds[t & 1] + BM * BK * 2;
    const int xo = (r16 & 7) << 4;       // read-side swizzle

    short8 af[8][2], bfr[2][2];
#pragma unroll
    for (int fm = 0; fm < 8; fm++)
#pragma unroll
      for (int kk = 0; kk < 2; kk++) {
        int row = wr * 128 + fm * 16 + r16;
        af[fm][kk] = *(const short8*)(sa + row * 128 + ((kk * 64 + g * 16) ^ xo));
      }
#pragma unroll
    for (int nq = 0; nq < 2; nq++)
#pragma unroll
      for (int kk = 0; kk < 2; kk++) {
        int row = wc * 32 + nq * 16 + r16;
        bfr[nq][kk] = *(const short8*)(sb + row * 128 + ((kk * 64 + g * 16) ^ xo));
      }

    __builtin_amdgcn_s_setprio(1);
#pragma unroll
    for (int fm = 0; fm < 8; fm++)
#pragma unroll
      for (int nq = 0; nq < 2; nq++)
#pragma unroll
        for (int kk = 0; kk < 2; kk++)
          acc[fm][nq] = __builtin_amdgcn_mfma_f32_16x16x32_bf16(
              af[fm][kk], bfr[nq][kk], acc[fm][nq], 0, 0, 0);
    __builtin_amdgcn_s_setprio(0);
  }

  // epilogue — verified C/D layout: col = lane&15, row = (lane>>4)*4 + j
  const int rw = g * 4;
#pragma unroll
  for (int am = 0; am < 8; am++) {
#pragma unroll
    for (int an = 0; an < 2; an++) {
      const int rg = m0 + wr * 128 + am * 16 + rw;
      const int cg = n0 + wc * 32 + an * 16 + r16;
      float bv = 0.f;
      if (BIAS) { if (blockIdx.z == 0) bv = bias[cg]; }
      if (VTOUT && cg >= 2 * D_) {       // V columns -> vT[h][d][s] (s = rg..rg+3)
        int hh = (cg - 2 * D_) >> 6, dd = (cg - 2 * D_) & 63;
        s16x4 ov;
#pragma unroll
        for (int j = 0; j < 4; j++) ov[j] = f2bf(acc[am][an][j]);
        *(s16x4*)&vTout[(size_t)hh * DH_ * S_ + (size_t)dd * S_ + rg] = ov;
      } else {
#pragma unroll
        for (int j = 0; j < 4; j++) {
          float v = acc[am][an][j] + bv;
          if (RELU) v = fmaxf(v, 0.f);
          if (OUTBF)
            ((short*)Cv + (long long)blockIdx.z * sCz)[(size_t)(rg + j) * ldc + cg] = f2bf(v);
          else
            ((float*)Cv + (long long)blockIdx.z * sCz)[(size_t)(rg + j) * ldc + cg] = v;
        }
      }
    }
  }
}

// ---------------------------------------------------------------------------
// Flash attention (causal, online softmax). 512 blocks, 256 threads.
// XCD-chunked swizzle: all 32 q-blocks of a head land on one XCD (K/V L2
// reuse); heavy q-blocks first within each XCD sequence.
// Swapped QK^T (mfma(K,Q)) -> score rows lane-local; P via wave-private LDS.
// K/V^T double-buffered; one barrier per KV step; setprio around MFMA (T5).
// (Verified R3/R8 body — R6 softmax restructure regressed +27us, reverted.)
// ---------------------------------------------------------------------------
__global__ __launch_bounds__(256, 4) void flash_attn(
    const short* __restrict__ qkv, const short* __restrict__ vT,
    short* __restrict__ attno)
{
  const int f = blockIdx.y * gridDim.x + blockIdx.x;
  const int xcd = f & 7, i = f >> 3;
  const int h  = xcd * 2 + (i >> 5);
  const int qb = (31 - (i & 31)) * 64;               // heavy blocks first
  const int tid = threadIdx.x, lane = tid & 63, w = tid >> 6;
  const int r16 = lane & 15, g = lane >> 4, kg = g * 8;

  __shared__ __align__(16) short kv_lds[2][2][64 * 64];
  __shared__ __align__(16) short p_lds[4][16 * 64];

  short8 qreg[2];
  {
    const short* qrow = qkv + (size_t)(qb + w * 16 + r16) * DQKV_ + h * DH_;
    qreg[0] = *(const short8*)&qrow[kg];
    qreg[1] = *(const short8*)&qrow[32 + kg];
  }

  const short* Ksec = qkv + D_ + h * DH_;
  const short* Vsec = vT + (size_t)h * DH_ * S_;

  auto stageKV = [&](int buf, int kv0) {
#pragma unroll
    for (int r = 0; r < 2; r++) {
      int p = r * 4096 + tid * 16;
      int q = swz128(p);
      int row = q >> 7, col = (q & 127) >> 1;
      gl2lds16(&Ksec[(size_t)(kv0 + row) * DQKV_ + col], (char*)kv_lds[buf][0] + p);
    }
#pragma unroll
    for (int r = 0; r < 2; r++) {
      int p = r * 4096 + tid * 16;
      int q = swz128(p);
      int row = q >> 7, col = (q & 127) >> 1;
      gl2lds16(&Vsec[(size_t)row * S_ + kv0 + col], (char*)kv_lds[buf][1] + p);
    }
  };

  f32x4 sacc[4], oacc[4];
#pragma unroll
  for (int m = 0; m < 4; m++) oacc[m] = f32x4{0.f, 0.f, 0.f, 0.f};
  float mrow = -3.0e38f, lrow = 0.f;
  const int qrow_g = qb + w * 16 + r16;
  const int nsteps = qb / 64 + 1;

  stageKV(0, 0);
  int cur = 0;
  for (int s = 0; s < nsteps; s++) {
    __syncthreads();
    if (s + 1 < nsteps) stageKV(cur ^ 1, (s + 1) * 64);

#pragma unroll
    for (int m = 0; m < 4; m++) sacc[m] = f32x4{0.f, 0.f, 0.f, 0.f};
    __builtin_amdgcn_s_setprio(1);
#pragma unroll
    for (int kk = 0; kk < 2; kk++) {
#pragma unroll
      for (int m = 0; m < 4; m++) {
        int lb = (m * 16 + r16) * 128 + (((kk * 32 + kg) * 2) ^ ((r16 & 7) << 4));
        short8 kf = *(const short8*)((const char*)kv_lds[cur][0] + lb);
        sacc[m] = __builtin_amdgcn_mfma_f32_16x16x32_bf16(kf, qreg[kk], sacc[m], 0, 0, 0);
      }
    }
    __builtin_amdgcn_s_setprio(0);

    const int kv0 = s * 64;
    const bool diag = (s == nsteps - 1);
    float mx = mrow;
#pragma unroll
    for (int m = 0; m < 4; m++)
#pragma unroll
      for (int j = 0; j < 4; j++) {
        float x = sacc[m][j] * 0.125f;
        if (diag && (kv0 + m * 16 + g * 4 + j > qrow_g)) x = -3.0e38f;
        sacc[m][j] = x;
        mx = fmaxf(mx, x);
      }
    mx = fmaxf(mx, __shfl_xor(mx, 16));
    mx = fmaxf(mx, __shfl_xor(mx, 32));
    float alpha = __expf(mrow - mx);
    mrow = mx;

    float psum = 0.f;
#pragma unroll
    for (int m = 0; m < 4; m++) {
      s16x4 pk;
#pragma unroll
      for (int j = 0; j < 4; j++) {
        float p = __expf(sacc[m][j] - mx);
        psum += p;
        pk[j] = f2bf(p);
      }
      *(s16x4*)((char*)p_lds[w] + r16 * 128 + (((m * 16 + g * 4) * 2) ^ ((r16 & 7) << 4))) = pk;
    }
    psum += __shfl_xor(psum, 16);
    psum += __shfl_xor(psum, 32);
    lrow = lrow * alpha + psum;

#pragma unroll
    for (int m = 0; m < 4; m++)
#pragma unroll
      for (int j = 0; j < 4; j++) oacc[m][j] *= alpha;

    __builtin_amdgcn_s_setprio(1);
#pragma unroll
    for (int kk = 0; kk < 2; kk++) {
      int pb = r16 * 128 + (((kk * 32 + kg) * 2) ^ ((r16 & 7) << 4));
      short8 pf = *(const short8*)((const char*)p_lds[w] + pb);
#pragma unroll
      for (int m = 0; m < 4; m++) {
        int vb = (m * 16 + r16) * 128 + (((kk * 32 + kg) * 2) ^ ((r16 & 7) << 4));
        short8 vf = *(const short8*)((const char*)kv_lds[cur][1] + vb);
        oacc[m] = __builtin_amdgcn_mfma_f32_16x16x32_bf16(vf, pf, oacc[m], 0, 0, 0);
      }
    }
    __builtin_amdgcn_s_setprio(0);
    cur ^= 1;
  }

  float inv = 1.0f / lrow;
  short* orow = attno + (size_t)qrow_g * D_ + h * DH_;
#pragma unroll
  for (int m = 0; m < 4; m++) {
    s16x4 ov;
#pragma unroll
    for (int j = 0; j < 4; j++) ov[j] = f2bf(oacc[m][j] * inv);
    *(s16x4*)&orow[m * 16 + g * 4] = ov;
  }
}

// ---------------------------------------------------------------------------
// Weight prep v3.1 (verified @942us): fp32 [K][N] -> bf16 GEMM-B tile blobs.
// One 128n x 64k tile per block, contiguous 16 KB blob in the physical
// (post-swizzle) LDS-staging order gemm8p consumes.
// Tiles/layer: QKV 3*128=384 + Wo 128 + W1 512 + W2 512 = 1536. grid(1536, L).
// Pinned at ~2.7-2.9 TB/s across 4 structural variants (R1/R3/R4) — the
// fp32->bf16 transpose at this size is structure-invariant; do not re-polish.
// R9: per-layer split cost +14us (worse machine fill + launch overhead) —
// single (1536, L) launch restored.
// ---------------------------------------------------------------------------
__global__ __launch_bounds__(256) void weight_prep(
    const float* __restrict__ Wq, const float* __restrict__ Wk,
    const float* __restrict__ Wv, const float* __restrict__ Wo,
    const float* __restrict__ W1, const float* __restrict__ W2,
    short* __restrict__ WqkvT, short* __restrict__ WoT,
    short* __restrict__ W1T, short* __restrict__ W2T)
{
  const int l = blockIdx.y, r = blockIdx.x;
  const float* src; short* dstb; int N, t, ks;
  if (r < 384) {
    int which = r >> 7; t = r & 127;
    src  = (which == 0 ? Wq : which == 1 ? Wk : Wv) + (size_t)l * D_ * D_;
    dstb = WqkvT + (size_t)l * DQKV_ * D_ + (size_t)which * D_ * D_;
    N = D_; ks = 4;
  } else if (r < 512) {
    t = r - 384;
    src = Wo + (size_t)l * D_ * D_; dstb = WoT + (size_t)l * D_ * D_;
    N = D_; ks = 4;
  } else if (r < 1024) {
    t = r - 512;
    src = W1 + (size_t)l * D_ * FF_; dstb = W1T + (size_t)l * D_ * FF_;
    N = FF_; ks = 4;
  } else {
    t = r - 1024;
    src = W2 + (size_t)l * D_ * FF_; dstb = W2T + (size_t)l * D_ * FF_;
    N = D_; ks = 6;
  }
  const int kT = 1 << ks;
  const int nt = t >> ks, kt = t & (kT - 1);
  const int n0 = nt * 128, k0 = kt * 64;
  short* out = dstb + ((size_t)nt * kT + kt) * (128 * 64);  // 16 KB blob

  // staging tile [k][n] bf16, pitch 130 shorts: phase-1 writes 2-way (free)
  __shared__ short tile[64][130];
  const int tid = threadIdx.x;

  // Phase 1: 64 rows x 128 cols fp32, 8 float4/thread, all in flight first
  {
    const int kr = tid >> 5;            // 0..7
    const int c4 = (tid & 31) * 4;      // 0..124
    const float* sp = &src[(size_t)(k0 + kr) * N + n0 + c4];
    float4 f[8];
#pragma unroll
    for (int i = 0; i < 8; i++) f[i] = *(const float4*)(sp + (size_t)i * 8 * N);
#pragma unroll
    for (int i = 0; i < 8; i++) {
      unsigned int* pw = (unsigned int*)&tile[kr + i * 8][c4];
      pw[0] = pack2bf(f[i].x, f[i].y);
      pw[1] = pack2bf(f[i].z, f[i].w);
    }
  }
  __syncthreads();

  // Phase 2: blob byte p -> logical q = swz128(p): n = q>>7, k = (q&127)>>1.
  // Gather 8 k-consecutive shorts of one n -> short8 -> linear 16B store.
#pragma unroll
  for (int rr = 0; rr < 4; rr++) {
    const int p = (rr * 256 + tid) * 16;
    const int q = swz128(p);
    const int n = q >> 7, k = (q & 127) >> 1;
    short8 o;
#pragma unroll
    for (int j = 0; j < 8; j++) o[j] = tile[k + j][n];
    *(short8*)((char*)out + p) = o;
  }
}

// ---------------------------------------------------------------------------
// Embedding + sinusoidal PE -> h fp32, hb bf16. grid = S, block = 256
// powf(1e4,e) -> exp2f(-13.2877*e): same value (verified passing in R6/R8).
// ---------------------------------------------------------------------------
__global__ __launch_bounds__(256) void embed_kernel(
    const int* __restrict__ tok, const float* __restrict__ emb,
    float* __restrict__ h, short* __restrict__ hb)
{
  int s = blockIdx.x, t = threadIdx.x;
  int token = tok[s];
  int d0 = t * 4;
  float4 e = *(const float4*)&emb[(size_t)token * D_ + d0];
  float o[4] = {e.x, e.y, e.z, e.w};
#pragma unroll
  for (int c = 0; c < 4; c++) {
    int d = d0 + c;
    float expo = (float)(d & ~1) / (float)D_;
    float ang  = (float)s * exp2f(expo * -13.287712379549449f);
    o[c] += (d & 1) ? cosf(ang) : sinf(ang);
  }
  float4 ov = {o[0], o[1], o[2], o[3]};
  *(float4*)&h[(size_t)s * D_ + d0] = ov;
  s16x4 sv = {f2bf(o[0]), f2bf(o[1]), f2bf(o[2]), f2bf(o[3])};
  *(s16x4*)&hb[(size_t)s * D_ + d0] = sv;
}

// ---------------------------------------------------------------------------
// out = LayerNorm(sum_z px[z] (bf16 partials) + x32 + res) * g + b
// fp32 out + optional bf16 outb. px or x32 may be null.
// ---------------------------------------------------------------------------
__global__ __launch_bounds__(256) void add_ln_kernel(
    const short* __restrict__ px, int nx, long long xs,
    const float* __restrict__ x32,
    const float* __restrict__ res,
    const float* __restrict__ g, const float* __restrict__ b,
    float* __restrict__ out, short* __restrict__ outb)
{
  int row = blockIdx.x, t = threadIdx.x;
  size_t base = (size_t)row * D_ + t * 4;
  float4 v = {0.f, 0.f, 0.f, 0.f};
  if (px) {
    for (int z = 0; z < nx; z++) {
      s16x4 r = *(const s16x4*)&px[(size_t)z * xs + base];
      v.x += bf2f(r[0]); v.y += bf2f(r[1]); v.z += bf2f(r[2]); v.w += bf2f(r[3]);
    }
  }
  if (x32) {
    float4 r = *(const float4*)&x32[base];
    v.x += r.x; v.y += r.y; v.z += r.z; v.w += r.w;
  }
  if (res) {
    float4 r = *(const float4*)&res[base];
    v.x += r.x; v.y += r.y; v.z += r.z; v.w += r.w;
  }
  float s  = v.x + v.y + v.z + v.w;
  float ss = v.x * v.x + v.y * v.y + v.z * v.z + v.w * v.w;
#pragma unroll
  for (int o = 32; o; o >>= 1) { s += __shfl_xor(s, o); ss += __shfl_xor(ss, o); }
  __shared__ float sh[8];
  int w = t >> 6;
  if ((t & 63) == 0) { sh[w] = s; sh[4 + w] = ss; }
  __syncthreads();
  s  = sh[0] + sh[1] + sh[2] + sh[3];
  ss = sh[4] + sh[5] + sh[6] + sh[7];
  float mean = s * (1.0f / D_);
  float var  = ss * (1.0f / D_) - mean * mean;
  float rinv = rsqrtf(var + 1e-5f);
  float4 gv = *(const float4*)&g[t * 4];
  float4 bv = *(const float4*)&b[t * 4];
  float4 ov;
  ov.x = (v.x - mean) * rinv * gv.x + bv.x;
  ov.y = (v.y - mean) * rinv * gv.y + bv.y;
  ov.z = (v.z - mean) * rinv * gv.z + bv.z;
  ov.w = (v.w - mean) * rinv * gv.w + bv.w;
  *(float4*)&out[base] = ov;
  if (outb) {
    s16x4 sv = {f2bf(ov.x), f2bf(ov.y), f2bf(ov.z), f2bf(ov.w)};
    *(s16x4*)&outb[base] = sv;
  }
}

__global__ void fill_kernel(float* out, int n, float v) {
  int i = blockIdx.x * 256 + threadIdx.x;
  if (i < n) out[i] = v;
}

// ---------------------------------------------------------------------------
extern "C" void kernel_launch(void* const* d_in, const int* in_sizes, int n_in,
                              void* d_out, int out_size, void* d_ws, size_t ws_size,
                              hipStream_t stream)
{
  const int*   tokens = (const int*)  d_in[0];
  const float* emb    = (const float*)d_in[1];
  const float* Wq     = (const float*)d_in[2];
  const float* Wk     = (const float*)d_in[3];
  const float* Wv     = (const float*)d_in[4];
  const float* Wo     = (const float*)d_in[5];
  const float* ln1_g  = (const float*)d_in[6];
  const float* ln1_b  = (const float*)d_in[7];
  const float* W1     = (const float*)d_in[8];
  const float* b1     = (const float*)d_in[9];
  const float* W2     = (const float*)d_in[10];
  const float* b2     = (const float*)d_in[11];
  const float* ln2_g  = (const float*)d_in[12];
  const float* ln2_b  = (const float*)d_in[13];
  const float* post_g = (const float*)d_in[14];
  const float* post_b = (const float*)d_in[15];

  size_t off = 0;
  auto alloc = [&](size_t bytes) -> char* {
    char* p = (char*)d_ws + off;
    off = (off + bytes + 255) & ~(size_t)255;
    return p;
  };
  short* WqkvT = (short*)alloc((size_t)L_ * DQKV_ * D_ * 2);
  short* WoT   = (short*)alloc((size_t)L_ * D_ * D_ * 2);
  short* W1T   = (short*)alloc((size_t)L_ * D_ * FF_ * 2);
  short* W2T   = (short*)alloc((size_t)L_ * D_ * FF_ * 2);
  float* h     = (float*)alloc((size_t)S_ * D_ * 4);
  short* hb    = (short*)alloc((size_t)S_ * D_ * 2);
  short* qkv   = (short*)alloc((size_t)S_ * DQKV_ * 2);
  short* vT    = (short*)alloc((size_t)S_ * D_ * 2);
  short* attno = (short*)alloc((size_t)S_ * D_ * 2);
  short* part  = (short*)alloc((size_t)4 * S_ * D_ * 2);   // bf16 split-K partials
  float* h1    = (float*)alloc((size_t)S_ * D_ * 4);
  short* h1b   = (short*)alloc((size_t)S_ * D_ * 2);
  short* m1    = (short*)alloc((size_t)S_ * FF_ * 2);

  if (off > ws_size) {
    fill_kernel<<<(out_size + 255) / 256, 256, 0, stream>>>(
        (float*)d_out, out_size, (float)(ws_size >> 20));
    return;
  }

  weight_prep<<<dim3(1536, L_), 256, 0, stream>>>(
      Wq, Wk, Wv, Wo, W1, W2, WqkvT, WoT, W1T, W2T);

  embed_kernel<<<S_, 256, 0, stream>>>(tokens, emb, h, hb);

  for (int l = 0; l < L_; l++) {
    const short* wqkv = WqkvT + (size_t)l * DQKV_ * D_;
    const short* wot  = WoT + (size_t)l * D_ * D_;
    const short* w1t  = W1T + (size_t)l * D_ * FF_;
    const short* w2t  = W2T + (size_t)l * D_ * FF_;

    // fused QKV: [2048,1024] x [3072,1024]^T; V columns go straight to vT
    gemm8p<false, false, true, true>
        <<<dim3(S_ / 256, DQKV_ / 128, 1), 512, 0, stream>>>(
            hb, D_, 0, wqkv, 16, 0, qkv, DQKV_, 0, nullptr, D_, vT);

    // fused causal attention -> attno [S][D]
    flash_attn<<<dim3(S_ / 64, H_), 256, 0, stream>>>(qkv, vT, attno);

    // o = attno @ Wo, split-K=4 -> bf16 partials (256 blocks)
    gemm8p<false, false, true, false>
        <<<dim3(S_ / 256, D_ / 128, 4), 512, 0, stream>>>(
            attno, D_, D_ / 4, wot, 16, 4,
            part, D_, (long long)S_ * D_, nullptr, D_ / 4, nullptr);

    add_ln_kernel<<<S_, 256, 0, stream>>>(part, 4, (long long)S_ * D_, nullptr, h,
                                          ln1_g + (size_t)l * D_,
                                          ln1_b + (size_t)l * D_, h1, h1b);

    // MLP1: relu(h1 @ W1 + b1) (256 blocks)
    gemm8p<true, true, true, false>
        <<<dim3(S_ / 256, FF_ / 128, 1), 512, 0, stream>>>(
            h1b, D_, 0, w1t, 16, 0, m1, FF_, 0, b1 + (size_t)l * FF_, D_, nullptr);

    // MLP2: m1 @ W2 + b2, split-K=4 -> bf16 partials (256 blocks)
    gemm8p<true, false, true, false>
        <<<dim3(S_ / 256, D_ / 128, 4), 512, 0, stream>>>(
            m1, FF_, FF_ / 4, w2t, 64, 16,
            part, D_, (long long)S_ * D_, b2 + (size_t)l * D_, FF_ / 4, nullptr);

    add_ln_kernel<<<S_, 256, 0, stream>>>(part, 4, (long long)S_ * D_, nullptr, h1,
                                          ln2_g + (size_t)l * D_,
                                          ln2_b + (size_t)l * D_, h, hb);
  }

  add_ln_kernel<<<S_, 256, 0, stream>>>(nullptr, 0, 0, h, nullptr, post_g, post_b,
                                        (float*)d_out, nullptr);
}